// Round 2
// baseline (308.325 us; speedup 1.0000x reference)
//
#include <hip/hip_runtime.h>
#include <hip/hip_bf16.h>
#include <stdint.h>

#define NUM_MODALS 4
#define SHARED_IDX 3

typedef __attribute__((ext_vector_type(8))) short bf16x8;
typedef __attribute__((ext_vector_type(4))) float floatx4;

__device__ __forceinline__ unsigned short f2bf(float f) {
  unsigned int u = __float_as_uint(f);
  u += 0x7fffu + ((u >> 16) & 1u);   // round-to-nearest-even
  return (unsigned short)(u >> 16);
}

// ---------------- W_eff build ----------------
// W_eff[m][o][c] = Wp[o][c] + sum_r Bw[3][o][r]*A[3][r][c] + sum_r Bw[m][o][r]*A[m][r][c]
// Round-2 change: 64 o-rows per block (was 16) -> grid (3,12,4)=144 blocks (was 576).
// Per-block fixed cost (dispatch, LDS fill, A-row loads) amortized 4x.
__global__ __launch_bounds__(256) void weff_fast(
    const float* __restrict__ Wp, const float* __restrict__ A,
    const float* __restrict__ Bw, unsigned short* __restrict__ Weff) {
  const int c  = blockIdx.x * 256 + threadIdx.x;
  const int o0 = blockIdx.y * 64;
  const int m  = blockIdx.z;

  __shared__ float b3[64 * 16], bm[64 * 16];
  const int t = threadIdx.x;
#pragma unroll
  for (int q = 0; q < 4; ++q) {
    const int idx = q * 256 + t;
    const int o = o0 + (idx >> 4);
    const int r = idx & 15;
    b3[idx] = Bw[(SHARED_IDX * 768 + o) * 16 + r];
    bm[idx] = Bw[((size_t)m * 768 + o) * 16 + r];
  }
  __syncthreads();

  float a3[16], am[16];
#pragma unroll
  for (int r = 0; r < 16; ++r) {
    a3[r] = A[(SHARED_IDX * 16 + r) * 768 + c];
    am[r] = A[((size_t)m * 16 + r) * 768 + c];
  }
#pragma unroll 4
  for (int oo = 0; oo < 64; ++oo) {
    const int o = o0 + oo;
    float acc = Wp[(size_t)o * 768 + c];
#pragma unroll
    for (int r = 0; r < 16; ++r) {
      acc += b3[oo * 16 + r] * a3[r];
      acc += bm[oo * 16 + r] * am[r];
    }
    Weff[((size_t)m * 768 + o) * 768 + c] = f2bf(acc);
  }
}

// ---------------- fused GEMM: out[m] = X[m] (fp32, cvt in-reg) * Weff[m]^T + bp ----
// Round-2 change: BM=256 x BN=128 tile, 512 threads, 8 waves (4M x 2N), BK=64.
// Inner structure is the proven round-0 single-buffer 2-barrier loop, unchanged:
//   stage W (glds w16) + stage X (float4 -> cvt_pk_bf16 -> XOR-swizzled ds_write)
//   -> barrier -> 2x{8 ds_read_b128 + 16 MFMA} per wave -> barrier.
// Rationale: per-block fixed overhead F (dispatch slot, prologue load latency,
// epilogue) measured ~15-20 kt-equivalents; halving block count (1536->768) and
// doubling MFMA per barrier interval amortizes F 2x and halves W traffic/FLOP.
// LDS 48 KB single-buffered -> 2 blocks/CU (launch_bounds(512,4) = 4 waves/EU).
// Grid 768 = 8 XCDs x 96: xcd chunk = 16 row-tiles x 6 col-tiles (X L2 reuse,
// one modality per 2 XCDs). 768 % 8 == 0 -> remap bijective.
__global__ __launch_bounds__(512, 4) void lora_gemm_fused(
    const float* __restrict__ X,
    const unsigned short* __restrict__ Weff,
    const float* __restrict__ bp,
    float* __restrict__ out) {
  const int bid = blockIdx.x;
  const int xcd = bid & 7;
  const int s   = bid >> 3;          // 0..95
  const int w   = xcd * 96 + s;      // contiguous per-XCD chunk
  const int ct  = w % 6;             // 6 col-tiles of 128
  const int rt  = w / 6;             // 0..127 row-tiles of 256
  const int m        = rt >> 5;      // 32 row-tiles per modality
  const int row_base = (rt & 31) * 256;
  const int col_base = ct * 128;

  __shared__ alignas(16) unsigned short As[256 * 64];  // 32 KB
  __shared__ alignas(16) unsigned short Ws[128 * 64];  // 16 KB

  const int tid  = threadIdx.x;
  const int wave = tid >> 6;         // 0..7
  const int lane = tid & 63;
  const int ln = lane & 15;
  const int qd = lane >> 4;
  const int wm = wave & 3;           // M quadrant (4)
  const int wn = wave >> 2;          // N half (2)

  const float*          Xm = X    + (size_t)m * 8192 * 768;
  const unsigned short* Wm = Weff + (size_t)m * 768 * 768;

  floatx4 acc[4][4];
#pragma unroll
  for (int i = 0; i < 4; ++i)
#pragma unroll
    for (int j = 0; j < 4; ++j)
      acc[i][j] = (floatx4)(0.0f);

  // --- X staging: thread covers (row xr+p*32, 4 fp32 cols at xc), p=0..7 ---
  const int xr   = tid >> 4;         // 0..31
  const int xc   = (tid & 15) * 4;   // 0..60
  const int cb   = xc >> 3;          // 16B col-block 0..7
  const int half = (xc >> 2) & 1;    // which 8B half of the block
  const float* xsrc[8];
  unsigned short* xdst[8];
#pragma unroll
  for (int p = 0; p < 8; ++p) {
    const int r = xr + p * 32;       // 0..255
    xsrc[p] = Xm + (size_t)(row_base + r) * 768 + xc;
    xdst[p] = &As[r * 64 + (cb ^ (r & 7)) * 8 + half * 4];
  }
  // --- W staging (global_load_lds w16: one issue = 8 rows x 128 B per wave) ---
  const int sr = lane >> 3;          // row-in-8
  const int ss = lane & 7;           // LDS slot this lane fills
  const unsigned short* wsrc[2];
#pragma unroll
  for (int p = 0; p < 2; ++p) {
    const int r = wave * 16 + p * 8 + sr;   // 0..127
    wsrc[p] = Wm + (size_t)(col_base + r) * 768 + (ss ^ (r & 7)) * 8;
  }

  for (int kt = 0; kt < 12; ++kt) {
#pragma unroll
    for (int p = 0; p < 2; ++p) {
      __builtin_amdgcn_global_load_lds(
          (const __attribute__((address_space(1))) void*)wsrc[p],
          (__attribute__((address_space(3))) void*)&Ws[(wave * 16 + p * 8) * 64],
          16, 0, 0);
      wsrc[p] += 64;
    }
#pragma unroll
    for (int p = 0; p < 8; ++p) {
      const float4 v = *(const float4*)xsrc[p];
      xsrc[p] += 64;
      __hip_bfloat162 h0 = __float22bfloat162_rn(make_float2(v.x, v.y));
      __hip_bfloat162 h1 = __float22bfloat162_rn(make_float2(v.z, v.w));
      uint2 hv;
      hv.x = *(unsigned int*)&h0;
      hv.y = *(unsigned int*)&h1;
      *(uint2*)xdst[p] = hv;
    }
    __syncthreads();

#pragma unroll
    for (int kk = 0; kk < 64; kk += 32) {
      const int kblk = (kk >> 3) + qd;           // 0..7
      const int slot = (kblk ^ (ln & 7)) * 8;
      bf16x8 a[4], b[4];
#pragma unroll
      for (int i = 0; i < 4; ++i)
        a[i] = *(const bf16x8*)(&As[(wm * 64 + i * 16 + ln) * 64 + slot]);
#pragma unroll
      for (int j = 0; j < 4; ++j)
        b[j] = *(const bf16x8*)(&Ws[(wn * 64 + j * 16 + ln) * 64 + slot]);
#pragma unroll
      for (int i = 0; i < 4; ++i)
#pragma unroll
        for (int j = 0; j < 4; ++j)
          acc[i][j] = __builtin_amdgcn_mfma_f32_16x16x32_bf16(a[i], b[j], acc[i][j], 0, 0, 0);
    }
    __syncthreads();
  }

  float* Om = out + (size_t)m * 8192 * 768;
#pragma unroll
  for (int j = 0; j < 4; ++j) {
    const int o = col_base + wn * 64 + j * 16 + ln;
    const float bias = bp[o];
#pragma unroll
    for (int i = 0; i < 4; ++i) {
      const int R = row_base + wm * 64 + i * 16 + qd * 4;
      float* dst = Om + (size_t)R * 768 + o;
#pragma unroll
      for (int v = 0; v < 4; ++v)
        dst[(size_t)v * 768] = acc[i][j][v] + bias;
    }
  }
}

extern "C" void kernel_launch(void* const* d_in, const int* in_sizes, int n_in,
                              void* d_out, int out_size, void* d_ws, size_t ws_size,
                              hipStream_t stream) {
  const float* x  = (const float*)d_in[0];   // [32, 1024, 768]
  const float* Wp = (const float*)d_in[1];   // [768, 768]
  const float* bp = (const float*)d_in[2];   // [768]
  const float* A  = (const float*)d_in[3];   // [4, 16, 768]
  const float* Bw = (const float*)d_in[4];   // [4, 768, 16]
  float* out = (float*)d_out;                // [32, 1024, 768]

  unsigned short* Weff = (unsigned short*)d_ws;  // [4][768][768] bf16 = 4.5 MB

  weff_fast<<<dim3(3, 12, 4), 256, 0, stream>>>(Wp, A, Bw, Weff);
  lora_gemm_fused<<<dim3(768), 512, 0, stream>>>(x, Weff, bp, out);
}

// Round 3
// 232.569 us; speedup vs baseline: 1.3257x; 1.3257x over previous
//
#include <hip/hip_runtime.h>
#include <hip/hip_bf16.h>
#include <stdint.h>

#define NUM_MODALS 4
#define SHARED_IDX 3

typedef __attribute__((ext_vector_type(8))) short bf16x8;
typedef __attribute__((ext_vector_type(4))) float floatx4;

__device__ __forceinline__ unsigned short f2bf(float f) {
  unsigned int u = __float_as_uint(f);
  u += 0x7fffu + ((u >> 16) & 1u);   // round-to-nearest-even
  return (unsigned short)(u >> 16);
}

// ---------------- W_eff build (round-0 proven version) ----------------
// W_eff[m][o][c] = Wp[o][c] + sum_r Bw[3][o][r]*A[3][r][c] + sum_r Bw[m][o][r]*A[m][r][c]
__global__ __launch_bounds__(256) void weff_fast(
    const float* __restrict__ Wp, const float* __restrict__ A,
    const float* __restrict__ Bw, unsigned short* __restrict__ Weff) {
  const int c  = blockIdx.x * 256 + threadIdx.x;
  const int o0 = blockIdx.y * 16;
  const int m  = blockIdx.z;

  __shared__ float b3[256], bm[256];   // 16 o-rows x 16 r, both adapters
  const int t = threadIdx.x;
  {
    const int o = o0 + (t >> 4);
    const int r = t & 15;
    b3[t] = Bw[(SHARED_IDX * 768 + o) * 16 + r];
    bm[t] = Bw[((size_t)m * 768 + o) * 16 + r];
  }
  __syncthreads();

  float a3[16], am[16];
#pragma unroll
  for (int r = 0; r < 16; ++r) {
    a3[r] = A[(SHARED_IDX * 16 + r) * 768 + c];
    am[r] = A[((size_t)m * 16 + r) * 768 + c];
  }
#pragma unroll 4
  for (int oo = 0; oo < 16; ++oo) {
    const int o = o0 + oo;
    float acc = Wp[(size_t)o * 768 + c];
#pragma unroll
    for (int r = 0; r < 16; ++r) {
      acc += b3[oo * 16 + r] * a3[r];
      acc += bm[oo * 16 + r] * am[r];
    }
    Weff[((size_t)m * 768 + o) * 768 + c] = f2bf(acc);
  }
}

// ---------------- fused GEMM: out[m] = X[m] (fp32, cvt in-reg) * Weff[m]^T + bp ----
// Round-3: round-0 geometry (128x128 tile, BK=64, 4 waves, 256 thr, grid 1536,
// same XOR swizzles / XCD remap) + T3/T4 counted-vmcnt pipeline:
//   - raw __builtin_amdgcn_s_barrier(), NEVER s_waitcnt vmcnt(0) in the loop
//   - X(kt+1) prefetched to registers mid-iter kt (in flight across compute(kt))
//   - W double-buffered via global_load_lds: W(kt+2)->Ws[kt&1] issued after
//     barrier-2 of iter kt, waited at top of iter kt+2
// Steady-state per-wave VMEM queue at iter top (issue order):
//   [W(kt):4, X(kt):8, W(kt+1):4]  ->  s_waitcnt vmcnt(4) retires W(kt)+X(kt)
// and leaves W(kt+1) in flight across the barrier. Last iter (kt=11) peeled
// logically: queue is [W11:4, X11:8] -> vmcnt(0) there (loop epilogue, one drain).
// Hazards: Ws[b] is rewritten (glds for kt+2) only after barrier-2 of iter kt;
// every wave's ds_reads of Ws[b]/As were consumed by pre-barrier MFMAs (their
// lgkm waits are before the MFMAs), so no wave can still read the buffer. As is
// single-buffered: its ds_writes at iter-kt top are ordered after barrier-2 of
// iter kt-1, by which point all compute(kt-1) reads retired.
// LDS = 16 KB (As) + 32 KB (Ws x2) = 48 KB -> 3 blocks/CU, 12 waves/CU.
__global__ __launch_bounds__(256) void lora_gemm_fused(
    const float* __restrict__ X,
    const unsigned short* __restrict__ Weff,
    const float* __restrict__ bp,
    float* __restrict__ out) {
  const int bid = blockIdx.x;
  const int xcd = bid & 7;
  const int s   = bid >> 3;          // 0..191
  const int w   = xcd * 192 + s;     // contiguous per-XCD chunk
  const int ct  = w % 6;
  const int rt  = w / 6;             // 0..255
  const int m        = rt >> 6;
  const int row_base = (rt & 63) * 128;
  const int col_base = ct * 128;

  __shared__ alignas(16) unsigned short As[128 * 64];       // 16 KB
  __shared__ alignas(16) unsigned short Ws[2 * 128 * 64];   // 32 KB

  const int tid  = threadIdx.x;
  const int wave = tid >> 6;
  const int lane = tid & 63;
  const int ln = lane & 15;
  const int qd = lane >> 4;
  const int wm = wave & 1;
  const int wn = wave >> 1;

  const float*          Xm = X    + (size_t)m * 8192 * 768;
  const unsigned short* Wm = Weff + (size_t)m * 768 * 768;

  floatx4 acc[4][4];
#pragma unroll
  for (int i = 0; i < 4; ++i)
#pragma unroll
    for (int j = 0; j < 4; ++j)
      acc[i][j] = (floatx4)(0.0f);

  // --- X staging geometry: thread covers (row xr+p*16, 4 fp32 cols at xc) ---
  const int xr   = tid >> 4;         // 0..15
  const int xc   = (tid & 15) * 4;   // 0..60
  const int cb   = xc >> 3;          // 16B col-block 0..7
  const int half = (xc >> 2) & 1;    // which 8B half of the block
  const float* xsrc[8];
  unsigned short* xdst[8];
#pragma unroll
  for (int p = 0; p < 8; ++p) {
    const int r = xr + p * 16;
    xsrc[p] = Xm + (size_t)(row_base + r) * 768 + xc;
    xdst[p] = &As[r * 64 + (cb ^ (r & 7)) * 8 + half * 4];
  }
  // --- W staging geometry (global_load_lds: 8 rows x 128 B per issue) ---
  const int sr = lane >> 3;          // row-in-8
  const int ss = lane & 7;           // LDS slot this lane fills
  const unsigned short* wsrc[4];
#pragma unroll
  for (int p = 0; p < 4; ++p) {
    const int r = wave * 32 + p * 8 + sr;
    wsrc[p] = Wm + (size_t)(col_base + r) * 768 + (ss ^ (r & 7)) * 8;
  }

  // ---- prologue: W(0)->Ws[0], X(0)->regs, W(1)->Ws[1] (issue order matters) ----
  float4 xv[8];
#pragma unroll
  for (int p = 0; p < 4; ++p) {
    __builtin_amdgcn_global_load_lds(
        (const __attribute__((address_space(1))) void*)wsrc[p],
        (__attribute__((address_space(3))) void*)&Ws[(wave * 32 + p * 8) * 64],
        16, 0, 0);
    wsrc[p] += 64;
  }
#pragma unroll
  for (int p = 0; p < 8; ++p) {
    xv[p] = *(const float4*)xsrc[p];
    xsrc[p] += 64;
  }
#pragma unroll
  for (int p = 0; p < 4; ++p) {
    __builtin_amdgcn_global_load_lds(
        (const __attribute__((address_space(1))) void*)wsrc[p],
        (__attribute__((address_space(3))) void*)&Ws[128 * 64 + (wave * 32 + p * 8) * 64],
        16, 0, 0);
    wsrc[p] += 64;
  }

  for (int kt = 0; kt < 12; ++kt) {
    const int boff = (kt & 1) * (128 * 64);

    // wait: retire W(kt) (so Ws[b] is valid past the barrier) and X(kt) (xv
    // usable). Keep W(kt+1) (4 ops) in flight across the barrier — the T4 move.
    if (kt < 11) {
      asm volatile("s_waitcnt vmcnt(4)" ::: "memory");
    } else {
      asm volatile("s_waitcnt vmcnt(0)" ::: "memory");
    }

    // convert + write X(kt) into As (loads were issued a full phase ago)
#pragma unroll
    for (int p = 0; p < 8; ++p) {
      const float4 v = xv[p];
      __hip_bfloat162 h0 = __float22bfloat162_rn(make_float2(v.x, v.y));
      __hip_bfloat162 h1 = __float22bfloat162_rn(make_float2(v.z, v.w));
      uint2 hv;
      hv.x = *(unsigned int*)&h0;
      hv.y = *(unsigned int*)&h1;
      *(uint2*)xdst[p] = hv;
    }

    // issue X(kt+1) -> regs (consumed at top of iter kt+1, hidden under compute)
    if (kt < 11) {
#pragma unroll
      for (int p = 0; p < 8; ++p) {
        xv[p] = *(const float4*)xsrc[p];
        xsrc[p] += 64;
      }
    }

    // barrier 1: As writes visible (lgkm drained), Ws[b] globally valid
    asm volatile("s_waitcnt lgkmcnt(0)" ::: "memory");
    __builtin_amdgcn_sched_barrier(0);
    __builtin_amdgcn_s_barrier();
    __builtin_amdgcn_sched_barrier(0);

    // compute(kt) on As / Ws[b]
    __builtin_amdgcn_s_setprio(1);
#pragma unroll
    for (int kk = 0; kk < 64; kk += 32) {
      const int kblk = (kk >> 3) + qd;           // 0..7
      const int slot = (kblk ^ (ln & 7)) * 8;
      bf16x8 a[4], b[4];
#pragma unroll
      for (int i = 0; i < 4; ++i)
        a[i] = *(const bf16x8*)(&As[(wm * 64 + i * 16 + ln) * 64 + slot]);
#pragma unroll
      for (int j = 0; j < 4; ++j)
        b[j] = *(const bf16x8*)(&Ws[boff + (wn * 64 + j * 16 + ln) * 64 + slot]);
#pragma unroll
      for (int i = 0; i < 4; ++i)
#pragma unroll
        for (int j = 0; j < 4; ++j)
          acc[i][j] = __builtin_amdgcn_mfma_f32_16x16x32_bf16(a[i], b[j], acc[i][j], 0, 0, 0);
    }
    __builtin_amdgcn_s_setprio(0);

    // barrier 2: every wave done reading Ws[b] / As -> safe to re-stage
    __builtin_amdgcn_sched_barrier(0);
    __builtin_amdgcn_s_barrier();
    __builtin_amdgcn_sched_barrier(0);

    // issue W(kt+2) -> Ws[b] (the buffer compute(kt) just vacated); stays in
    // flight through all of iter kt+1, waited at top of iter kt+2.
    if (kt < 10) {
#pragma unroll
      for (int p = 0; p < 4; ++p) {
        __builtin_amdgcn_global_load_lds(
            (const __attribute__((address_space(1))) void*)wsrc[p],
            (__attribute__((address_space(3))) void*)&Ws[boff + (wave * 32 + p * 8) * 64],
            16, 0, 0);
        wsrc[p] += 64;
      }
    }
  }

  float* Om = out + (size_t)m * 8192 * 768;
#pragma unroll
  for (int j = 0; j < 4; ++j) {
    const int o = col_base + wn * 64 + j * 16 + ln;
    const float bias = bp[o];
#pragma unroll
    for (int i = 0; i < 4; ++i) {
      const int R = row_base + wm * 64 + i * 16 + qd * 4;
      float* dst = Om + (size_t)R * 768 + o;
#pragma unroll
      for (int v = 0; v < 4; ++v)
        dst[(size_t)v * 768] = acc[i][j][v] + bias;
    }
  }
}

extern "C" void kernel_launch(void* const* d_in, const int* in_sizes, int n_in,
                              void* d_out, int out_size, void* d_ws, size_t ws_size,
                              hipStream_t stream) {
  const float* x  = (const float*)d_in[0];   // [32, 1024, 768]
  const float* Wp = (const float*)d_in[1];   // [768, 768]
  const float* bp = (const float*)d_in[2];   // [768]
  const float* A  = (const float*)d_in[3];   // [4, 16, 768]
  const float* Bw = (const float*)d_in[4];   // [4, 768, 16]
  float* out = (float*)d_out;                // [32, 1024, 768]

  unsigned short* Weff = (unsigned short*)d_ws;  // [4][768][768] bf16 = 4.5 MB

  weff_fast<<<dim3(3, 48, 4), 256, 0, stream>>>(Wp, A, Bw, Weff);
  lora_gemm_fused<<<dim3(1536), 256, 0, stream>>>(x, Weff, bp, out);
}